// Round 2
// baseline (430.046 us; speedup 1.0000x reference)
//
#include <hip/hip_runtime.h>
#include <stdint.h>

// Cost volume = 48-wide band of Gram matrix L^T R per (b,h), K = c = 128.
// bf16 MFMA 32x32x16. Memory-bound target ~47us (298 MB @ 6.3 TB/s).
// R6: occupancy fix. Epilogue transpose chunked (2 x 24 disparities) so
//     per-wave scratch (24*33 f32) fits inside the 40 KB staging region.
//     LDS 63488 -> 40960 B => 3 blocks/CU (30 waves), grid 768 = 3*256
//     exactly one residency round. Staging = proven R4 reg-pack path;
//     stage s+2 loads issued before the MFMA cluster.

typedef __bf16 bf16x8 __attribute__((ext_vector_type(8)));
typedef float floatx16 __attribute__((ext_vector_type(16)));

constexpr int W = 320, H = 96, C = 128, NB = 8, MAXD = 48;
constexpr int HW = H * W;        // 30720
constexpr int SC = 16;           // c-rows per stage
constexpr int MATD = 8 * W;      // packed dwords per matrix per stage = 2560
constexpr int BUFD = 2 * MATD;   // dwords per buffer (L+R) = 5120 (20 KB)
constexpr int NST = C / SC;      // 8 stages
constexpr int ECH = 24;          // epilogue disparity chunk
constexpr int ESZ = ECH * 33;    // per-wave scratch dwords = 792

__device__ __forceinline__ uint32_t pack_bf16x2(float a, float b) {
    // RNE f32->bf16; (c even -> low16, c odd -> high16) == MFMA k-order.
    uint32_t ua = __float_as_uint(a), ub = __float_as_uint(b);
    uint32_t lo = (ua + 0x7fffu + ((ua >> 16) & 1u)) >> 16;
    uint32_t hi = (ub + 0x7fffu + ((ub >> 16) & 1u)) & 0xffff0000u;
    return hi | lo;
}

__device__ __forceinline__ void soft_barrier() {
    // Execution barrier + LDS visibility WITHOUT vmcnt(0) drain:
    // global prefetch loads stay in flight across it.
    asm volatile("s_waitcnt lgkmcnt(0)" ::: "memory");
    __builtin_amdgcn_s_barrier();
    asm volatile("" ::: "memory");
}

__global__ __launch_bounds__(640, 8) void cost_volume_kernel(
    const float* __restrict__ Lg, const float* __restrict__ Rg,
    float* __restrict__ out)
{
    // 40960 B: two 20 KB stage buffers, reused by the chunked epilogue
    // scratch (10 waves * 792 dwords = 7920 dwords <= 10240).
    __shared__ uint32_t lds[2 * BUFD];

    const int t    = threadIdx.x;
    const int lane = t & 63;
    const int p    = t >> 6;       // wave id = 32-wide x-tile id
    const int n    = lane & 31;
    const int half = lane >> 5;

    const int b = blockIdx.x / H;
    const int h = blockIdx.x % H;
    const int baseLR = b * (C * HW) + h * W;

    // staging: thread t covers c-pair row rp (c = 2rp, 2rp+1), cols 4*c4..+3
    const int rp = t / 80;         // 0..7
    const int c4 = t % 80;
    const float* Lt = Lg + baseLR + 2 * rp * HW + 4 * c4;
    const float* Rt = Rg + baseLR + 2 * rp * HW + 4 * c4;

    float4 l0, l1, r0, r1;         // prefetch regs (16 VGPR)

    auto loadStage = [&](int s) {
        const float* Lp = Lt + s * SC * HW;
        const float* Rp = Rt + s * SC * HW;
        l0 = *(const float4*)(Lp);
        l1 = *(const float4*)(Lp + HW);
        r0 = *(const float4*)(Rp);
        r1 = *(const float4*)(Rp + HW);
    };

    auto writeLDS = [&](uint32_t* buf) {
        uint32_t* d = buf + rp * W + 4 * c4;
        uint4 v;
        v.x = pack_bf16x2(l0.x, l1.x);
        v.y = pack_bf16x2(l0.y, l1.y);
        v.z = pack_bf16x2(l0.z, l1.z);
        v.w = pack_bf16x2(l0.w, l1.w);
        *reinterpret_cast<uint4*>(d) = v;
        v.x = pack_bf16x2(r0.x, r1.x);
        v.y = pack_bf16x2(r0.y, r1.y);
        v.z = pack_bf16x2(r0.z, r1.z);
        v.w = pack_bf16x2(r0.w, r1.w);
        *reinterpret_cast<uint4*>(d + MATD) = v;
    };

    floatx16 acc0 = 0.f, acc1 = 0.f, acc2 = 0.f;  // q = p, p-1, p-2

    loadStage(0);
    writeLDS(lds);            // buf0 <- stage 0 (vmcnt waits via dependency)
    loadStage(1);             // stage 1 in flight across the barrier
    soft_barrier();

#pragma unroll 1
    for (int s = 0; s < NST; ++s) {
        const uint32_t* sL = lds + (s & 1) * BUFD;
        const uint32_t* sR = sL + MATD;

        // A fragment: k = half*8 + j -> c-pair rows half*4 + jj
        const uint32_t* pa = sL + half * 4 * W + p * 32 + n;
        uint4 a4;
        a4.x = pa[0 * W]; a4.y = pa[1 * W]; a4.z = pa[2 * W]; a4.w = pa[3 * W];
        bf16x8 af = __builtin_bit_cast(bf16x8, a4);

        uint4 b40, b41, b42;
        {
            const uint32_t* pb = sR + half * 4 * W + p * 32 + n;
            b40.x = pb[0 * W]; b40.y = pb[1 * W]; b40.z = pb[2 * W]; b40.w = pb[3 * W];
        }
        if (p >= 1) {
            const uint32_t* pb = sR + half * 4 * W + (p - 1) * 32 + n;
            b41.x = pb[0 * W]; b41.y = pb[1 * W]; b41.z = pb[2 * W]; b41.w = pb[3 * W];
        }
        if (p >= 2) {
            const uint32_t* pb = sR + half * 4 * W + (p - 2) * 32 + n;
            b42.x = pb[0 * W]; b42.y = pb[1 * W]; b42.z = pb[2 * W]; b42.w = pb[3 * W];
        }

        // consume stage s+1 regs into the other buffer, then issue stage
        // s+2 loads -> in flight across the MFMAs AND the barrier.
        if (s < NST - 1) writeLDS(lds + ((s + 1) & 1) * BUFD);
        if (s < NST - 2) loadStage(s + 2);

        acc0 = __builtin_amdgcn_mfma_f32_32x32x16_bf16(
            af, __builtin_bit_cast(bf16x8, b40), acc0, 0, 0, 0);
        if (p >= 1)
            acc1 = __builtin_amdgcn_mfma_f32_32x32x16_bf16(
                af, __builtin_bit_cast(bf16x8, b41), acc1, 0, 0, 0);
        if (p >= 2)
            acc2 = __builtin_amdgcn_mfma_f32_32x32x16_bf16(
                af, __builtin_bit_cast(bf16x8, b42), acc2, 0, 0, 0);

        soft_barrier();
    }

    __syncthreads();   // full drain before reusing LDS as scratch

    // ---- epilogue: band -> per-wave LDS transpose -> coalesced stores ----
    // D layout (verified): x = 32p + m, m = (r&3) + 8*(r>>2) + 4*half,
    // i = 32*DP + m - n. Chunked over disparity (2 x 24) so scratch fits
    // in the staging LDS footprint.
    float* sS = reinterpret_cast<float*>(lds) + p * ESZ;
    const int ob = b * (MAXD * HW) + h * W + p * 32;
    constexpr float scale = 1.f / 128.f;

#pragma unroll 1
    for (int k = 0; k < MAXD / ECH; ++k) {
        if (k) asm volatile("s_waitcnt lgkmcnt(0)" ::: "memory");

        if (p < 2) {  // only x<64 has an i>x zero triangle
            for (int e = lane; e < ESZ; e += 64) sS[e] = 0.f;
        }

#define FILL_TILE(DP, ACC)                                                  \
        if (p >= (DP)) {                                                    \
            _Pragma("unroll")                                               \
            for (int r = 0; r < 16; ++r) {                                  \
                int m = (r & 3) + 8 * (r >> 2) + 4 * half;                  \
                int il = 32 * (DP) + m - n - ECH * k;                       \
                if (il >= 0 && il < ECH)                                    \
                    sS[il * 33 + m] = ACC[r] * scale;                       \
            }                                                               \
        }
        FILL_TILE(0, acc0)
        FILL_TILE(1, acc1)
        FILL_TILE(2, acc2)
#undef FILL_TILE

#pragma unroll
        for (int e = 0; e < ECH * 32 / 64; ++e) {
            int idx = e * 64 + lane;
            int il = idx >> 5;       // chunk-local disparity 0..23
            int m  = idx & 31;       // x-local
            out[ob + (ECH * k + il) * HW + m] = sS[il * 33 + m];
        }
    }
}

extern "C" void kernel_launch(void* const* d_in, const int* in_sizes, int n_in,
                              void* d_out, int out_size, void* d_ws, size_t ws_size,
                              hipStream_t stream) {
    const float* L = (const float*)d_in[0];
    const float* R = (const float*)d_in[1];
    float* out = (float*)d_out;
    cost_volume_kernel<<<dim3(NB * H), dim3(640), 0, stream>>>(L, R, out);
}

// Round 3
// 278.688 us; speedup vs baseline: 1.5431x; 1.5431x over previous
//
#include <hip/hip_runtime.h>
#include <stdint.h>

// Cost volume = 48-wide band of Gram matrix L^T R per (b,h), K = c = 128.
// bf16 MFMA 32x32x16. Memory-bound target ~47us (298 MB @ 6.3 TB/s).
// R7: R6's 40 KB LDS plan (3 blocks/CU by LDS) + R4's register discipline
//     (launch_bounds(640,5): 44 VGPR + 48 acc, NO spill — R6's (640,8)
//     spilled accumulators: WRITE_SIZE 46->582 MB, 2.8x regression).
//     Epilogue chunked 2 x 24 disparities to fit scratch in 40 KB.

typedef __bf16 bf16x8 __attribute__((ext_vector_type(8)));
typedef float floatx16 __attribute__((ext_vector_type(16)));

constexpr int W = 320, H = 96, C = 128, NB = 8, MAXD = 48;
constexpr int HW = H * W;        // 30720
constexpr int SC = 16;           // c-rows per stage
constexpr int MATD = 8 * W;      // packed dwords per matrix per stage = 2560
constexpr int BUFD = 2 * MATD;   // dwords per buffer (L+R) = 5120 (20 KB)
constexpr int NST = C / SC;      // 8 stages
constexpr int ECH = 24;          // epilogue disparity chunk
constexpr int ESZ = ECH * 33;    // per-wave scratch dwords = 792

__device__ __forceinline__ uint32_t pack_bf16x2(float a, float b) {
    // RNE f32->bf16; (c even -> low16, c odd -> high16) == MFMA k-order.
    uint32_t ua = __float_as_uint(a), ub = __float_as_uint(b);
    uint32_t lo = (ua + 0x7fffu + ((ua >> 16) & 1u)) >> 16;
    uint32_t hi = (ub + 0x7fffu + ((ub >> 16) & 1u)) & 0xffff0000u;
    return hi | lo;
}

__device__ __forceinline__ void soft_barrier() {
    // Execution barrier + LDS visibility WITHOUT vmcnt(0) drain:
    // global prefetch loads stay in flight across it.
    asm volatile("s_waitcnt lgkmcnt(0)" ::: "memory");
    __builtin_amdgcn_s_barrier();
    asm volatile("" ::: "memory");
}

__global__ __launch_bounds__(640, 5) void cost_volume_kernel(
    const float* __restrict__ Lg, const float* __restrict__ Rg,
    float* __restrict__ out)
{
    // 40960 B: two 20 KB stage buffers, reused by the chunked epilogue
    // scratch (10 waves * 792 dwords = 7920 dwords <= 10240).
    __shared__ uint32_t lds[2 * BUFD];

    const int t    = threadIdx.x;
    const int lane = t & 63;
    const int p    = t >> 6;       // wave id = 32-wide x-tile id
    const int n    = lane & 31;
    const int half = lane >> 5;

    const int b = blockIdx.x / H;
    const int h = blockIdx.x % H;
    const int baseLR = b * (C * HW) + h * W;

    // staging: thread t covers c-pair row rp (c = 2rp, 2rp+1), cols 4*c4..+3
    const int rp = t / 80;         // 0..7
    const int c4 = t % 80;
    const float* Lt = Lg + baseLR + 2 * rp * HW + 4 * c4;
    const float* Rt = Rg + baseLR + 2 * rp * HW + 4 * c4;

    float4 l0, l1, r0, r1;         // prefetch regs (16 VGPR)

    auto loadStage = [&](int s) {
        const float* Lp = Lt + s * SC * HW;
        const float* Rp = Rt + s * SC * HW;
        l0 = *(const float4*)(Lp);
        l1 = *(const float4*)(Lp + HW);
        r0 = *(const float4*)(Rp);
        r1 = *(const float4*)(Rp + HW);
    };

    auto writeLDS = [&](uint32_t* buf) {
        uint32_t* d = buf + rp * W + 4 * c4;
        uint4 v;
        v.x = pack_bf16x2(l0.x, l1.x);
        v.y = pack_bf16x2(l0.y, l1.y);
        v.z = pack_bf16x2(l0.z, l1.z);
        v.w = pack_bf16x2(l0.w, l1.w);
        *reinterpret_cast<uint4*>(d) = v;
        v.x = pack_bf16x2(r0.x, r1.x);
        v.y = pack_bf16x2(r0.y, r1.y);
        v.z = pack_bf16x2(r0.z, r1.z);
        v.w = pack_bf16x2(r0.w, r1.w);
        *reinterpret_cast<uint4*>(d + MATD) = v;
    };

    floatx16 acc0 = 0.f, acc1 = 0.f, acc2 = 0.f;  // q = p, p-1, p-2

    loadStage(0);
    writeLDS(lds);            // buf0 <- stage 0 (vmcnt waits via dependency)
    loadStage(1);             // stage 1 in flight across the barrier
    soft_barrier();

#pragma unroll 1
    for (int s = 0; s < NST; ++s) {
        const uint32_t* sL = lds + (s & 1) * BUFD;
        const uint32_t* sR = sL + MATD;

        // A fragment: k = half*8 + j -> c-pair rows half*4 + jj
        const uint32_t* pa = sL + half * 4 * W + p * 32 + n;
        uint4 a4;
        a4.x = pa[0 * W]; a4.y = pa[1 * W]; a4.z = pa[2 * W]; a4.w = pa[3 * W];
        bf16x8 af = __builtin_bit_cast(bf16x8, a4);

        uint4 b40, b41, b42;
        {
            const uint32_t* pb = sR + half * 4 * W + p * 32 + n;
            b40.x = pb[0 * W]; b40.y = pb[1 * W]; b40.z = pb[2 * W]; b40.w = pb[3 * W];
        }
        if (p >= 1) {
            const uint32_t* pb = sR + half * 4 * W + (p - 1) * 32 + n;
            b41.x = pb[0 * W]; b41.y = pb[1 * W]; b41.z = pb[2 * W]; b41.w = pb[3 * W];
        }
        if (p >= 2) {
            const uint32_t* pb = sR + half * 4 * W + (p - 2) * 32 + n;
            b42.x = pb[0 * W]; b42.y = pb[1 * W]; b42.z = pb[2 * W]; b42.w = pb[3 * W];
        }

        // consume stage s+1 regs into the other buffer, then issue stage
        // s+2 loads -> in flight across the MFMAs AND the barrier.
        if (s < NST - 1) writeLDS(lds + ((s + 1) & 1) * BUFD);
        if (s < NST - 2) loadStage(s + 2);

        acc0 = __builtin_amdgcn_mfma_f32_32x32x16_bf16(
            af, __builtin_bit_cast(bf16x8, b40), acc0, 0, 0, 0);
        if (p >= 1)
            acc1 = __builtin_amdgcn_mfma_f32_32x32x16_bf16(
                af, __builtin_bit_cast(bf16x8, b41), acc1, 0, 0, 0);
        if (p >= 2)
            acc2 = __builtin_amdgcn_mfma_f32_32x32x16_bf16(
                af, __builtin_bit_cast(bf16x8, b42), acc2, 0, 0, 0);

        soft_barrier();
    }

    __syncthreads();   // full drain before reusing LDS as scratch

    // ---- epilogue: band -> per-wave LDS transpose -> coalesced stores ----
    // D layout (verified): x = 32p + m, m = (r&3) + 8*(r>>2) + 4*half,
    // i = 32*DP + m - n. Chunked over disparity (2 x 24) so scratch fits
    // in the staging LDS footprint. Scratch is per-wave-private, so no
    // cross-wave barrier is needed between chunks (lgkmcnt covers the
    // own-wave LDS reads of the previous chunk's stores).
    float* sS = reinterpret_cast<float*>(lds) + p * ESZ;
    const int ob = b * (MAXD * HW) + h * W + p * 32;
    constexpr float scale = 1.f / 128.f;

#pragma unroll 1
    for (int k = 0; k < MAXD / ECH; ++k) {
        if (k) asm volatile("s_waitcnt lgkmcnt(0)" ::: "memory");

        if (p < 2) {  // only x<64 has an i>x zero triangle
            for (int e = lane; e < ESZ; e += 64) sS[e] = 0.f;
        }

#define FILL_TILE(DP, ACC)                                                  \
        if (p >= (DP)) {                                                    \
            _Pragma("unroll")                                               \
            for (int r = 0; r < 16; ++r) {                                  \
                int m = (r & 3) + 8 * (r >> 2) + 4 * half;                  \
                int il = 32 * (DP) + m - n - ECH * k;                       \
                if (il >= 0 && il < ECH)                                    \
                    sS[il * 33 + m] = ACC[r] * scale;                       \
            }                                                               \
        }
        FILL_TILE(0, acc0)
        FILL_TILE(1, acc1)
        FILL_TILE(2, acc2)
#undef FILL_TILE

#pragma unroll
        for (int e = 0; e < ECH * 32 / 64; ++e) {
            int idx = e * 64 + lane;
            int il = idx >> 5;       // chunk-local disparity 0..23
            int m  = idx & 31;       // x-local
            out[ob + (ECH * k + il) * HW + m] = sS[il * 33 + m];
        }
    }
}

extern "C" void kernel_launch(void* const* d_in, const int* in_sizes, int n_in,
                              void* d_out, int out_size, void* d_ws, size_t ws_size,
                              hipStream_t stream) {
    const float* L = (const float*)d_in[0];
    const float* R = (const float*)d_in[1];
    float* out = (float*)d_out;
    cost_volume_kernel<<<dim3(NB * H), dim3(640), 0, stream>>>(L, R, out);
}

// Round 5
// 275.931 us; speedup vs baseline: 1.5585x; 1.0100x over previous
//
#include <hip/hip_runtime.h>
#include <stdint.h>

// Cost volume = 48-wide band of Gram matrix L^T R per (b,h), K = c = 128.
// bf16 MFMA 32x32x16. Memory-bound target ~47us (298 MB @ 6.3 TB/s).
// R9 (= R8 resubmitted; the R8 bench died to an infra "container failed
// twice" error before running — kernel audited memory/hang-safe).
// Barrier-free streaming: the staged/lockstep family (R4-R7) is pinned at
// ~111us (2 resident 10-wave blocks, all waves stall together at stage
// barriers; reg file caps residency; R6 proved 3 blocks => spill; FETCH
// 125MB < compulsory 252MB => inputs L3-resident, so cross-wave sharing
// buys nothing). New shape: one INDEPENDENT wave per 32-x tile; A + 3 B
// fragments loaded straight from global (per-lane strided dwords, 128B
// coalesced per half-wave), packed f32->bf16 in regs, double-buffered one
// stage ahead. No s_barrier anywhere. LDS only as per-wave epilogue scratch.

typedef __bf16 bf16x8 __attribute__((ext_vector_type(8)));
typedef float floatx16 __attribute__((ext_vector_type(16)));

constexpr int W = 320, H = 96, C = 128, NB = 8, MAXD = 48;
constexpr int HW = H * W;          // 30720
constexpr int SC = 16;             // channels per stage
constexpr int NST = C / SC;        // 8 stages
constexpr int TPP = W / 32;        // x-tiles per (b,h) plane = 10
constexpr int NTASK = NB * H * TPP;  // 7680 wave-tasks
constexpr int WPB = 4;             // waves per block (no coupling, just packing)
constexpr int ESZ = MAXD * 33;     // per-wave epilogue scratch dwords = 1584

__device__ __forceinline__ uint32_t pack_bf16x2(float a, float b) {
    // RNE f32->bf16; (c even -> low16, c odd -> high16) == MFMA k-order.
    uint32_t ua = __float_as_uint(a), ub = __float_as_uint(b);
    uint32_t lo = (ua + 0x7fffu + ((ua >> 16) & 1u)) >> 16;
    uint32_t hi = (ub + 0x7fffu + ((ub >> 16) & 1u)) & 0xffff0000u;
    return hi | lo;
}

__device__ __forceinline__ bf16x8 packf(const float* v) {
    uint4 q;
    q.x = pack_bf16x2(v[0], v[1]);
    q.y = pack_bf16x2(v[2], v[3]);
    q.z = pack_bf16x2(v[4], v[5]);
    q.w = pack_bf16x2(v[6], v[7]);
    return __builtin_bit_cast(bf16x8, q);
}

__global__ __launch_bounds__(256, 3) void cost_volume_kernel(
    const float* __restrict__ Lg, const float* __restrict__ Rg,
    float* __restrict__ out)
{
    __shared__ float scr[WPB * ESZ];   // 25344 B: per-wave-private scratch

    const int t    = threadIdx.x;
    const int lane = t & 63;
    const int w    = t >> 6;
    const int n    = lane & 31;
    const int half = lane >> 5;

    const int wid   = blockIdx.x * WPB + w;   // wave-task id
    const int plane = wid / TPP;
    const int p     = wid % TPP;              // x-tile index (x0 = 32p)
    const int b     = plane / H;
    const int h     = plane % H;

    const int baseLR = b * (C * HW) + h * W;
    // per-lane offset: c-row 8*half + j (j via pointer), column 32p + n.
    const int lofs = (8 * half) * HW + p * 32 + n;
    const float* Ap  = Lg + baseLR + lofs;      // A  = L tile p
    const float* Bp0 = Rg + baseLR + lofs;      // B0 = R tile p
    const float* Bp1 = Bp0 - 32;                // B1 = R tile p-1 (guarded)
    const float* Bp2 = Bp0 - 64;                // B2 = R tile p-2 (guarded)

    // double-buffered raw f32 fragments (64 VGPR)
    float a_[2][8], b0_[2][8], b1_[2][8], b2_[2][8];

#define LOAD_STAGE(BUF, S)                                                  \
    {                                                                       \
        const int o = (S) * SC * HW;                                        \
        _Pragma("unroll")                                                   \
        for (int j = 0; j < 8; ++j) a_[BUF][j] = Ap[o + j * HW];            \
        _Pragma("unroll")                                                   \
        for (int j = 0; j < 8; ++j) b0_[BUF][j] = Bp0[o + j * HW];          \
        if (p >= 1) {                                                       \
            _Pragma("unroll")                                               \
            for (int j = 0; j < 8; ++j) b1_[BUF][j] = Bp1[o + j * HW];      \
        }                                                                   \
        if (p >= 2) {                                                       \
            _Pragma("unroll")                                               \
            for (int j = 0; j < 8; ++j) b2_[BUF][j] = Bp2[o + j * HW];      \
        }                                                                   \
    }

    floatx16 acc0 = 0.f, acc1 = 0.f, acc2 = 0.f;  // q = p, p-1, p-2

    LOAD_STAGE(0, 0)

#pragma unroll
    for (int s = 0; s < NST; ++s) {
        const int cur = s & 1;          // static after full unroll
        const int nxt = cur ^ 1;
        if (s + 1 < NST) LOAD_STAGE(nxt, s + 1)   // 32 loads stay in flight
        // across the packs+MFMAs below (compiler emits counted vmcnt).
        bf16x8 af = packf(a_[cur]);
        acc0 = __builtin_amdgcn_mfma_f32_32x32x16_bf16(
            af, packf(b0_[cur]), acc0, 0, 0, 0);
        if (p >= 1)
            acc1 = __builtin_amdgcn_mfma_f32_32x32x16_bf16(
                af, packf(b1_[cur]), acc1, 0, 0, 0);
        if (p >= 2)
            acc2 = __builtin_amdgcn_mfma_f32_32x32x16_bf16(
                af, packf(b2_[cur]), acc2, 0, 0, 0);
    }
#undef LOAD_STAGE

    // ---- epilogue: band -> per-wave LDS transpose -> coalesced stores ----
    // D layout (verified): x = 32p + m, m = (r&3) + 8*(r>>2) + 4*half,
    // i = 32*DP + m - n. Scratch is wave-private: no barriers needed
    // (compiler orders ds_write -> ds_read via lgkmcnt).
    float* sS = scr + w * ESZ;
    const int ob = b * (MAXD * HW) + h * W + p * 32;
    constexpr float scale = 1.f / 128.f;

    if (p < 2) {  // only x<64 has an i>x zero triangle
        for (int e = lane; e < ESZ; e += 64) sS[e] = 0.f;
    }

#define FILL_TILE(DP, ACC)                                                  \
    if (p >= (DP)) {                                                        \
        _Pragma("unroll")                                                   \
        for (int r = 0; r < 16; ++r) {                                      \
            int m = (r & 3) + 8 * (r >> 2) + 4 * half;                      \
            int i = 32 * (DP) + m - n;                                      \
            if (i >= 0 && i < MAXD)                                         \
                sS[i * 33 + m] = ACC[r] * scale;                            \
        }                                                                   \
    }
    FILL_TILE(0, acc0)
    FILL_TILE(1, acc1)
    FILL_TILE(2, acc2)
#undef FILL_TILE

#pragma unroll
    for (int e = 0; e < 24; ++e) {
        int idx = e * 64 + lane;
        int i = idx >> 5;        // disparity 0..47
        int m = idx & 31;        // x-local
        out[ob + i * HW + m] = sS[i * 33 + m];
    }
}

extern "C" void kernel_launch(void* const* d_in, const int* in_sizes, int n_in,
                              void* d_out, int out_size, void* d_ws, size_t ws_size,
                              hipStream_t stream) {
    const float* L = (const float*)d_in[0];
    const float* R = (const float*)d_in[1];
    float* out = (float*)d_out;
    cost_volume_kernel<<<dim3(NTASK / WPB), dim3(64 * WPB), 0, stream>>>(L, R, out);
}